// Round 12
// baseline (16772.717 us; speedup 1.0000x reference)
//
#include <hip/hip_runtime.h>
#include <hip/hip_cooperative_groups.h>

namespace cgr = cooperative_groups;

#define N_DIM 100000
#define M_DIM 200000
#define NNZ_A 2000000
#define NNZ_P 500000
#define NMSUM 300000
#define NM1   300001
#define CG_ITERS 20
#define TPB 256
#define NSLOT 512
#define GRID_C 512

// slots: sc[0]=xTPx, sc[1..3]=dd_t dots, sc[8..9]=rhs-FTmv dots,
// per-iter base 16+8*it: {d1,d2,e1,e2,pq}, gam[] at sc+432 (0..50)

__device__ __forceinline__ void blk_red_add(double v, double* dst) {
    __shared__ double sb[TPB];
    int tid = threadIdx.x;
    __syncthreads();
    sb[tid] = v;
    __syncthreads();
    for (int sh = TPB / 2; sh > 0; sh >>= 1) {
        if (tid < sh) sb[tid] += sb[tid + sh];
        __syncthreads();
    }
    if (tid == 0) atomicAdd(dst, sb[0]);
}

// ---------- setup kernels (identical math to the passing R11 version) ----------
__global__ __launch_bounds__(TPB) void k_init(double* sc, const float* y, const float* s,
                                              double* mask_d, double* pim_d, double* Px,
                                              double* dpx, double* dd, double* r,
                                              double* xcg, double* tm) {
    int i = blockIdx.x * TPB + threadIdx.x;
    if (i < NSLOT) sc[i] = 0.0;
    if (i < M_DIM) {
        double v = (double)y[i] - (double)s[i];
        mask_d[i] = v > 0.0 ? 1.0 : 0.0;
        pim_d[i]  = v > 0.0 ? v : 0.0;
        tm[i] = 0.0;
    }
    if (i < N_DIM) { Px[i] = 0.0; dpx[i] = 0.0; }
    if (i < NM1) { dd[i] = 0.0; r[i] = 0.0; xcg[i] = 0.0; }
}

__global__ __launch_bounds__(TPB) void k_sp(const float* vals, const int* rows, const int* cols,
                                            const double* vin, double* vout, double sgn, long nnz) {
    long k = (long)blockIdx.x * TPB + threadIdx.x;
    if (k < nnz) atomicAdd(&vout[rows[k]], sgn * (double)vals[k] * vin[cols[k]]);
}
__global__ __launch_bounds__(TPB) void k_spf(const float* vals, const int* rows, const int* cols,
                                             const float* vin, double* vout, double sgn, long nnz) {
    long k = (long)blockIdx.x * TPB + threadIdx.x;
    if (k < nnz) atomicAdd(&vout[rows[k]], sgn * (double)vals[k] * (double)vin[cols[k]]);
}

__global__ __launch_bounds__(TPB) void k_dot_dd(const double* a, const double* b, long len, double* dst) {
    long i = (long)blockIdx.x * TPB + threadIdx.x;
    double loc = 0.0;
    if (i < len) loc = a[i] * b[i];
    blk_red_add(loc, dst);
}
__global__ __launch_bounds__(TPB) void k_dot_fd(const float* a, const double* b, long len, double* dst) {
    long i = (long)blockIdx.x * TPB + threadIdx.x;
    double loc = 0.0;
    if (i < len) loc = (double)a[i] * b[i];
    blk_red_add(loc, dst);
}
__global__ __launch_bounds__(TPB) void k_dot_ff(const float* a, const float* b, long len, double* dst) {
    long i = (long)blockIdx.x * TPB + threadIdx.x;
    double loc = 0.0;
    if (i < len) loc = (double)a[i] * (double)b[i];
    blk_red_add(loc, dst);
}

__global__ __launch_bounds__(TPB) void k_c3e(const float* q, const double* Px, double* c3) {
    int i = blockIdx.x * TPB + threadIdx.x;
    if (i < N_DIM) c3[i] = (double)q[i] + 2.0 * Px[i];
}
__global__ __launch_bounds__(TPB) void k_dd_n(const double* dpx, const float* dq, double* dd) {
    int i = blockIdx.x * TPB + threadIdx.x;
    if (i < N_DIM) dd[i] = dpx[i] + (double)dq[i];
}
__global__ __launch_bounds__(TPB) void k_dd_m(const float* db, double* dd) {
    int j = blockIdx.x * TPB + threadIdx.x;
    if (j < M_DIM) dd[N_DIM + j] += (double)db[j];
}
__global__ __launch_bounds__(64) void k_dd_t(double* sc, double* dd) {
    if (threadIdx.x == 0) dd[NMSUM] = -sc[1] - sc[2] - sc[3];
}
__global__ __launch_bounds__(TPB) void k_neg(double* dd) {
    int i = blockIdx.x * TPB + threadIdx.x;
    if (i < NM1) dd[i] = -dd[i];
}
__global__ __launch_bounds__(TPB) void k_ft_n(const double* c3, const double* W, double* U) {
    int i = blockIdx.x * TPB + threadIdx.x;
    if (i < N_DIM) U[i] = U[i] - c3[i] * W[NMSUM];
}
__global__ __launch_bounds__(TPB) void k_ft_m(const double* mask_d, const float* b,
                                              const double* tm, const double* W, double* U) {
    int j = blockIdx.x * TPB + threadIdx.x;
    if (j < M_DIM) {
        double wt = W[NMSUM];
        double tmv = tm[j] - (double)b[j] * wt;
        double wm = W[N_DIM + j];
        U[N_DIM + j] = mask_d[j] * (tmv - wm) + wm;
    }
}
__global__ __launch_bounds__(64) void k_ft_t(const double* e1, const double* e2, const double* xtpx,
                                             const double* W, double* U) {
    if (threadIdx.x == 0) U[NMSUM] = (*e1) + (*e2) + (*xtpx) * W[NMSUM];
}
__global__ __launch_bounds__(TPB) void k_cginit(const double* r, double* p, double* gam0) {
    int i = blockIdx.x * TPB + threadIdx.x;
    double loc = 0.0;
    if (i < NM1) { double v = r[i]; p[i] = v; loc = v * v; }
    blk_red_add(loc, gam0);
}

// ---------- cooperative CG loop: 20 iterations, 7 grid syncs each ----------
__global__ __launch_bounds__(TPB) void k_cg_loop(
    const int* __restrict__ Pr, const int* __restrict__ Pc, const float* __restrict__ Pv,
    const int* __restrict__ Ar, const int* __restrict__ Ac, const float* __restrict__ Av,
    const float* __restrict__ q, const float* __restrict__ b,
    const double* __restrict__ mask_d, const double* __restrict__ c3,
    double* sc, double* um, double* tm,
    double* r, double* p, double* xcg, double* Fp, double* Ap)
{
    cgr::grid_group grid = cgr::this_grid();
    const long tid = (long)blockIdx.x * TPB + threadIdx.x;
    const long NT  = (long)gridDim.x * TPB;
    const double* xtpx = sc;
    double* gam = sc + 432;

    for (int it = 0; it < CG_ITERS; ++it) {
        double* d1 = sc + 16 + 8 * it;
        double* d2 = d1 + 1;
        double* e1 = d1 + 2;
        double* e2 = d1 + 3;
        double* pq = d1 + 4;

        // ---- Phase A: p-update (it>0) + um + zero Fp/Ap_n/tm ----
        if (it > 0) {
            double beta = gam[it] / gam[it - 1];
            for (long i = tid; i < NM1; i += NT) {
                double pn = r[i] + beta * p[i];
                p[i] = pn;
                if (i >= N_DIM && i < NMSUM) um[i - N_DIM] = mask_d[i - N_DIM] * pn;
            }
        } else {
            for (long i = tid; i < NM1; i += NT)
                if (i >= N_DIM && i < NMSUM) um[i - N_DIM] = mask_d[i - N_DIM] * p[i];
        }
        for (long i = tid; i < NM1; i += NT) Fp[i] = 0.0;
        for (long i = tid; i < N_DIM; i += NT) Ap[i] = 0.0;
        for (long j = tid; j < M_DIM; j += NT) tm[j] = 0.0;
        grid.sync();

        // ---- Phase B: Fmv scatters + dots d1 = c3.p_n, d2 = b.um ----
        for (long k = tid; k < NNZ_P; k += NT)
            atomicAdd(&Fp[Pr[k]], (double)Pv[k] * p[Pc[k]]);
        for (long k = tid; k < NNZ_A; k += NT) {
            atomicAdd(&Fp[Ac[k]], (double)Av[k] * um[Ar[k]]);           // + A^T um
            atomicAdd(&Fp[N_DIM + Ar[k]], -(double)Av[k] * p[Ac[k]]);   // - A p_n
        }
        {
            double l1 = 0.0, l2 = 0.0;
            for (long i = tid; i < N_DIM; i += NT) l1 += c3[i] * p[i];
            for (long j = tid; j < M_DIM; j += NT) l2 += (double)b[j] * um[j];
            blk_red_add(l1, d1);
            blk_red_add(l2, d2);
        }
        grid.sync();

        // ---- Phase C: Fmv elementwise finish (literal forms) ----
        {
            double ut = p[NMSUM];
            for (long i = tid; i < N_DIM; i += NT) {
                double r1 = Fp[i] + (double)q[i] * ut;
                Fp[i] = (r1 - p[i]) + p[i];
            }
            for (long j = tid; j < M_DIM; j += NT) {
                double r2 = Fp[N_DIM + j] + (double)b[j] * ut;
                Fp[N_DIM + j] = (r2 - um[j]) + p[N_DIM + j];
            }
            if (tid == 0) {
                double r3 = -(*d1) - (*d2) + (*xtpx) * ut;
                Fp[NMSUM] = (r3 - ut) + ut;
            }
        }
        grid.sync();

        // ---- Phase D: FTmv scatters + dots e1 = q.Fp_n, e2 = b.Fp_m ----
        for (long k = tid; k < NNZ_P; k += NT)
            atomicAdd(&Ap[Pr[k]], (double)Pv[k] * Fp[Pc[k]]);
        for (long k = tid; k < NNZ_A; k += NT) {
            atomicAdd(&Ap[Ac[k]], -(double)Av[k] * Fp[N_DIM + Ar[k]]);  // - A^T wm
            atomicAdd(&tm[Ar[k]], (double)Av[k] * Fp[Ac[k]]);           // + A wn
        }
        {
            double l1 = 0.0, l2 = 0.0;
            for (long i = tid; i < N_DIM; i += NT) l1 += (double)q[i] * Fp[i];
            for (long j = tid; j < M_DIM; j += NT) l2 += (double)b[j] * Fp[N_DIM + j];
            blk_red_add(l1, e1);
            blk_red_add(l2, e2);
        }
        grid.sync();

        // ---- Phase E: FTmv elementwise finish ----
        {
            double wt = Fp[NMSUM];
            for (long i = tid; i < N_DIM; i += NT) Ap[i] = Ap[i] - c3[i] * wt;
            for (long j = tid; j < M_DIM; j += NT) {
                double tmv = tm[j] - (double)b[j] * wt;
                double wm = Fp[N_DIM + j];
                Ap[N_DIM + j] = mask_d[j] * (tmv - wm) + wm;
            }
            if (tid == 0) Ap[NMSUM] = (*e1) + (*e2) + (*xtpx) * wt;
        }
        grid.sync();

        // ---- Phase F: pq = p . Ap ----
        {
            double l = 0.0;
            for (long i = tid; i < NM1; i += NT) l += p[i] * Ap[i];
            blk_red_add(l, pq);
        }
        grid.sync();

        // ---- Phase G: x,r update + gam[it+1] ----
        {
            double alpha = gam[it] / (*pq);
            double l = 0.0;
            for (long i = tid; i < NM1; i += NT) {
                xcg[i] += alpha * p[i];
                double rn = r[i] - alpha * Ap[i];
                r[i] = rn;
                l += rn * rn;
            }
            blk_red_add(l, &gam[it + 1]);
        }
        grid.sync();
    }
}

__global__ __launch_bounds__(TPB) void k_final(const double* xcg, const double* mask_d,
                                               const float* x, const float* y, const float* s,
                                               float* out) {
    int i = blockIdx.x * TPB + threadIdx.x;
    double dzt = xcg[NMSUM];
    if (i < N_DIM) {
        out[i] = (float)(xcg[i] - (double)x[i] * dzt);
    } else if (i < NMSUM) {
        int j = i - N_DIM;
        double dzm = xcg[N_DIM + j];
        double t = mask_d[j] * dzm;
        out[N_DIM + j] = (float)(t - (double)y[j] * dzt);
        out[N_DIM + M_DIM + j] = (float)(t - dzm - (double)s[j] * dzt);
    }
}

extern "C" void kernel_launch(void* const* d_in, const int* in_sizes, int n_in,
                              void* d_out, int out_size, void* d_ws, size_t ws_size,
                              hipStream_t stream) {
    const int*   Pr  = (const int*)d_in[0];
    const int*   Pc  = (const int*)d_in[1];
    const float* Pv  = (const float*)d_in[2];
    const int*   Ar  = (const int*)d_in[3];
    const int*   Ac  = (const int*)d_in[4];
    const float* Av  = (const float*)d_in[5];
    const float* q   = (const float*)d_in[6];
    const float* b   = (const float*)d_in[7];
    const float* x   = (const float*)d_in[8];
    const float* yv  = (const float*)d_in[9];
    const float* sv  = (const float*)d_in[10];
    const float* dPv = (const float*)d_in[11];
    const float* dAv = (const float*)d_in[12];
    const float* dq  = (const float*)d_in[13];
    const float* db  = (const float*)d_in[14];
    float* out = (float*)d_out;

    char* wp = (char*)d_ws;
    double* sc     = (double*)wp; wp += NSLOT * 8;
    double* mask_d = (double*)wp; wp += M_DIM * 8;
    double* pim_d  = (double*)wp; wp += M_DIM * 8;
    double* Px     = (double*)wp; wp += N_DIM * 8;
    double* dpx    = (double*)wp; wp += N_DIM * 8;
    double* c3     = (double*)wp; wp += N_DIM * 8;
    double* um     = (double*)wp; wp += M_DIM * 8;
    double* tm     = (double*)wp; wp += M_DIM * 8;
    double* dd     = (double*)wp; wp += NM1 * 8;
    double* r      = (double*)wp; wp += NM1 * 8;
    double* p      = (double*)wp; wp += NM1 * 8;
    double* xcg    = (double*)wp; wp += NM1 * 8;
    double* Fp     = (double*)wp; wp += NM1 * 8;
    double* Ap     = (double*)wp; wp += NM1 * 8;

    double* xtpx = sc + 0;
    double* gam  = sc + 432;

    auto g = [](long n) { return dim3((unsigned)((n + TPB - 1) / TPB)); };

    // ---- setup (identical to passing R11 sequence) ----
    hipLaunchKernelGGL(k_init, g(NM1), dim3(TPB), 0, stream, sc, yv, sv, mask_d, pim_d, Px, dpx, dd, r, xcg, tm);
    hipLaunchKernelGGL(k_spf, g(NNZ_P), dim3(TPB), 0, stream, Pv, Pr, Pc, x, Px, 1.0, (long)NNZ_P);
    hipLaunchKernelGGL(k_dot_fd, g(N_DIM), dim3(TPB), 0, stream, x, Px, (long)N_DIM, xtpx);
    hipLaunchKernelGGL(k_c3e, g(N_DIM), dim3(TPB), 0, stream, q, Px, c3);
    hipLaunchKernelGGL(k_spf, g(NNZ_P), dim3(TPB), 0, stream, dPv, Pr, Pc, x, dpx, 1.0, (long)NNZ_P);
    hipLaunchKernelGGL(k_dd_n, g(N_DIM), dim3(TPB), 0, stream, dpx, dq, dd);
    hipLaunchKernelGGL(k_sp, g(NNZ_A), dim3(TPB), 0, stream, dAv, Ac, Ar, pim_d, dd, 1.0, (long)NNZ_A);
    hipLaunchKernelGGL(k_spf, g(NNZ_A), dim3(TPB), 0, stream, dAv, Ar, Ac, x, dd + N_DIM, -1.0, (long)NNZ_A);
    hipLaunchKernelGGL(k_dd_m, g(M_DIM), dim3(TPB), 0, stream, db, dd);
    hipLaunchKernelGGL(k_dot_ff, g(N_DIM), dim3(TPB), 0, stream, dq, x, (long)N_DIM, sc + 1);
    hipLaunchKernelGGL(k_dot_fd, g(M_DIM), dim3(TPB), 0, stream, db, pim_d, (long)M_DIM, sc + 2);
    hipLaunchKernelGGL(k_dot_fd, g(N_DIM), dim3(TPB), 0, stream, x, dpx, (long)N_DIM, sc + 3);
    hipLaunchKernelGGL(k_dd_t, dim3(1), dim3(64), 0, stream, sc, dd);
    hipLaunchKernelGGL(k_neg, g(NM1), dim3(TPB), 0, stream, dd);
    hipLaunchKernelGGL(k_sp, g(NNZ_P), dim3(TPB), 0, stream, Pv, Pr, Pc, dd, r, 1.0, (long)NNZ_P);
    hipLaunchKernelGGL(k_sp, g(NNZ_A), dim3(TPB), 0, stream, Av, Ac, Ar, dd + N_DIM, r, -1.0, (long)NNZ_A);
    hipLaunchKernelGGL(k_ft_n, g(N_DIM), dim3(TPB), 0, stream, c3, dd, r);
    hipLaunchKernelGGL(k_sp, g(NNZ_A), dim3(TPB), 0, stream, Av, Ar, Ac, dd, tm, 1.0, (long)NNZ_A);
    hipLaunchKernelGGL(k_ft_m, g(M_DIM), dim3(TPB), 0, stream, mask_d, b, tm, dd, r);
    hipLaunchKernelGGL(k_dot_fd, g(N_DIM), dim3(TPB), 0, stream, q, dd, (long)N_DIM, sc + 8);
    hipLaunchKernelGGL(k_dot_fd, g(M_DIM), dim3(TPB), 0, stream, b, dd + N_DIM, (long)M_DIM, sc + 9);
    hipLaunchKernelGGL(k_ft_t, dim3(1), dim3(64), 0, stream, sc + 8, sc + 9, xtpx, dd, r);
    hipLaunchKernelGGL(k_cginit, g(NM1), dim3(TPB), 0, stream, r, p, gam);

    // ---- 20 CG iterations in one cooperative kernel ----
    void* args[] = {
        (void*)&Pr, (void*)&Pc, (void*)&Pv, (void*)&Ar, (void*)&Ac, (void*)&Av,
        (void*)&q, (void*)&b, (void*)&mask_d, (void*)&c3,
        (void*)&sc, (void*)&um, (void*)&tm,
        (void*)&r, (void*)&p, (void*)&xcg, (void*)&Fp, (void*)&Ap
    };
    hipLaunchCooperativeKernel((const void*)k_cg_loop, dim3(GRID_C), dim3(TPB), args, 0, stream);

    hipLaunchKernelGGL(k_final, g(NMSUM), dim3(TPB), 0, stream, xcg, mask_d, x, yv, sv, out);
}

// Round 13
// 10530.768 us; speedup vs baseline: 1.5927x; 1.5927x over previous
//
#include <hip/hip_runtime.h>

#define N_DIM 100000
#define M_DIM 200000
#define NNZ_A 2000000
#define NNZ_P 500000
#define NMSUM 300000
#define NM1   300001
#define CG_ITERS 20
#define TPB 256
#define NSLOT 512

// slots: sc[0]=xTPx, sc[1..3]=dd_t dots, sc[8..9]=rhs-FTmv dots,
// per-iter base 16+8*it: {d1,d2,e1,e2,pq}, gam[] at sc+432 (0..50)

__device__ __forceinline__ void blk_red_add(double v, double* dst) {
    __shared__ double sb[TPB];
    int tid = threadIdx.x;
    __syncthreads();
    sb[tid] = v;
    __syncthreads();
    for (int sh = TPB / 2; sh > 0; sh >>= 1) {
        if (tid < sh) sb[tid] += sb[tid + sh];
        __syncthreads();
    }
    if (tid == 0) atomicAdd(dst, sb[0]);
}

// ---------- setup kernels (identical math to passing R11) ----------
__global__ __launch_bounds__(TPB) void k_init(double* sc, const float* y, const float* s,
                                              double* mask_d, double* pim_d, double* Px,
                                              double* dpx, double* dd, double* r,
                                              double* xcg, double* tm) {
    int i = blockIdx.x * TPB + threadIdx.x;
    if (i < NSLOT) sc[i] = 0.0;
    if (i < M_DIM) {
        double v = (double)y[i] - (double)s[i];
        mask_d[i] = v > 0.0 ? 1.0 : 0.0;
        pim_d[i]  = v > 0.0 ? v : 0.0;
        tm[i] = 0.0;
    }
    if (i < N_DIM) { Px[i] = 0.0; dpx[i] = 0.0; }
    if (i < NM1) { dd[i] = 0.0; r[i] = 0.0; xcg[i] = 0.0; }
}

__global__ __launch_bounds__(TPB) void k_sp(const float* vals, const int* rows, const int* cols,
                                            const double* vin, double* vout, double sgn, long nnz) {
    long k = (long)blockIdx.x * TPB + threadIdx.x;
    if (k < nnz) atomicAdd(&vout[rows[k]], sgn * (double)vals[k] * vin[cols[k]]);
}
__global__ __launch_bounds__(TPB) void k_spf(const float* vals, const int* rows, const int* cols,
                                             const float* vin, double* vout, double sgn, long nnz) {
    long k = (long)blockIdx.x * TPB + threadIdx.x;
    if (k < nnz) atomicAdd(&vout[rows[k]], sgn * (double)vals[k] * (double)vin[cols[k]]);
}

__global__ __launch_bounds__(TPB) void k_dot_fd(const float* a, const double* b, long len, double* dst) {
    long i = (long)blockIdx.x * TPB + threadIdx.x;
    double loc = 0.0;
    if (i < len) loc = (double)a[i] * b[i];
    blk_red_add(loc, dst);
}
__global__ __launch_bounds__(TPB) void k_dot_ff(const float* a, const float* b, long len, double* dst) {
    long i = (long)blockIdx.x * TPB + threadIdx.x;
    double loc = 0.0;
    if (i < len) loc = (double)a[i] * (double)b[i];
    blk_red_add(loc, dst);
}

__global__ __launch_bounds__(TPB) void k_c3e(const float* q, const double* Px, double* c3) {
    int i = blockIdx.x * TPB + threadIdx.x;
    if (i < N_DIM) c3[i] = (double)q[i] + 2.0 * Px[i];
}
__global__ __launch_bounds__(TPB) void k_dd_n(const double* dpx, const float* dq, double* dd) {
    int i = blockIdx.x * TPB + threadIdx.x;
    if (i < N_DIM) dd[i] = dpx[i] + (double)dq[i];
}
__global__ __launch_bounds__(TPB) void k_dd_m(const float* db, double* dd) {
    int j = blockIdx.x * TPB + threadIdx.x;
    if (j < M_DIM) dd[N_DIM + j] += (double)db[j];
}
__global__ __launch_bounds__(64) void k_dd_t(double* sc, double* dd) {
    if (threadIdx.x == 0) dd[NMSUM] = -sc[1] - sc[2] - sc[3];
}
__global__ __launch_bounds__(TPB) void k_neg(double* dd) {
    int i = blockIdx.x * TPB + threadIdx.x;
    if (i < NM1) dd[i] = -dd[i];
}
__global__ __launch_bounds__(TPB) void k_ft_n(const double* c3, const double* W, double* U) {
    int i = blockIdx.x * TPB + threadIdx.x;
    if (i < N_DIM) U[i] = U[i] - c3[i] * W[NMSUM];
}
__global__ __launch_bounds__(TPB) void k_ft_m(const double* mask_d, const float* b,
                                              const double* tm, const double* W, double* U) {
    int j = blockIdx.x * TPB + threadIdx.x;
    if (j < M_DIM) {
        double wt = W[NMSUM];
        double tmv = tm[j] - (double)b[j] * wt;
        double wm = W[N_DIM + j];
        U[N_DIM + j] = mask_d[j] * (tmv - wm) + wm;
    }
}
__global__ __launch_bounds__(64) void k_ft_t(const double* e1, const double* e2, const double* xtpx,
                                             const double* W, double* U) {
    if (threadIdx.x == 0) U[NMSUM] = (*e1) + (*e2) + (*xtpx) * W[NMSUM];
}
__global__ __launch_bounds__(TPB) void k_cginit(const double* r, double* p, double* gam0) {
    int i = blockIdx.x * TPB + threadIdx.x;
    double loc = 0.0;
    if (i < NM1) { double v = r[i]; p[i] = v; loc = v * v; }
    blk_red_add(loc, gam0);
}

// ---------- fused per-iteration kernels (6 launches/iter) ----------
// K1: p-update + um + zero Fp/Ap_n/tm + d1 = c3.p_n, d2 = b.um
__global__ __launch_bounds__(TPB) void k_iterA(const double* r, double* p,
                                               const double* mask_d, const double* c3,
                                               const float* b, double* um,
                                               double* Fp, double* Ap, double* tm,
                                               double* sc, int it) {
    long i = (long)blockIdx.x * TPB + threadIdx.x;
    double* gam = sc + 432;
    double* base = sc + 16 + 8 * it;
    double l1 = 0.0, l2 = 0.0;
    if (i < NM1) {
        double pn;
        if (it > 0) {
            double beta = gam[it] / gam[it - 1];
            pn = r[i] + beta * p[i];
            p[i] = pn;
        } else {
            pn = p[i];
        }
        if (i < N_DIM) {
            l1 = c3[i] * pn;
            Ap[i] = 0.0;
        } else if (i < NMSUM) {
            int j = (int)(i - N_DIM);
            double u = mask_d[j] * pn;
            um[j] = u;
            l2 = (double)b[j] * u;
        }
        Fp[i] = 0.0;
        if (i < M_DIM) tm[i] = 0.0;
    }
    blk_red_add(l1, base);       // d1
    blk_red_add(l2, base + 1);   // d2
}

// K2: Fmv scatter — P once, A indices read once for both products
__global__ __launch_bounds__(TPB) void k_fmv_scat(const int* __restrict__ Pr, const int* __restrict__ Pc,
                                                  const float* __restrict__ Pv,
                                                  const int* __restrict__ Ar, const int* __restrict__ Ac,
                                                  const float* __restrict__ Av,
                                                  const double* __restrict__ p, const double* __restrict__ um,
                                                  double* Fp) {
    long k = (long)blockIdx.x * TPB + threadIdx.x;
    if (k < NNZ_P)
        atomicAdd(&Fp[Pr[k]], (double)Pv[k] * p[Pc[k]]);
    if (k < NNZ_A) {
        int ar = Ar[k], ac = Ac[k];
        double av = (double)Av[k];
        atomicAdd(&Fp[ac], av * um[ar]);              // + A^T um
        atomicAdd(&Fp[N_DIM + ar], -av * p[ac]);      // - A p_n
    }
}

// K3: Fmv elementwise finish (literal forms) + e1 = q.Fp_n, e2 = b.Fp_m
__global__ __launch_bounds__(TPB) void k_fmv_fin(const float* q, const float* b,
                                                 const double* p, const double* um,
                                                 double* Fp, double* sc, int it) {
    long i = (long)blockIdx.x * TPB + threadIdx.x;
    double* base = sc + 16 + 8 * it;
    double ut = p[NMSUM];
    double l1 = 0.0, l2 = 0.0;
    if (i < N_DIM) {
        double r1 = Fp[i] + (double)q[i] * ut;
        double v = (r1 - p[i]) + p[i];
        Fp[i] = v;
        l1 = (double)q[i] * v;
    } else if (i < NMSUM) {
        int j = (int)(i - N_DIM);
        double r2 = Fp[i] + (double)b[j] * ut;
        double v = (r2 - um[j]) + p[i];
        Fp[i] = v;
        l2 = (double)b[j] * v;
    } else if (i == NMSUM) {
        double r3 = -base[0] - base[1] + sc[0] * ut;
        Fp[NMSUM] = (r3 - ut) + ut;
    }
    blk_red_add(l1, base + 2);   // e1
    blk_red_add(l2, base + 3);   // e2
}

// K4: FTmv scatter — P once, A indices once for both products
__global__ __launch_bounds__(TPB) void k_ftmv_scat(const int* __restrict__ Pr, const int* __restrict__ Pc,
                                                   const float* __restrict__ Pv,
                                                   const int* __restrict__ Ar, const int* __restrict__ Ac,
                                                   const float* __restrict__ Av,
                                                   const double* __restrict__ Fp,
                                                   double* Ap, double* tm) {
    long k = (long)blockIdx.x * TPB + threadIdx.x;
    if (k < NNZ_P)
        atomicAdd(&Ap[Pr[k]], (double)Pv[k] * Fp[Pc[k]]);
    if (k < NNZ_A) {
        int ar = Ar[k], ac = Ac[k];
        double av = (double)Av[k];
        atomicAdd(&Ap[ac], -av * Fp[N_DIM + ar]);     // - A^T wm
        atomicAdd(&tm[ar], av * Fp[ac]);              // + A wn
    }
}

// K5: FTmv elementwise finish + pq = p . Ap
__global__ __launch_bounds__(TPB) void k_ftmv_fin(const float* b, const double* mask_d,
                                                  const double* c3, const double* tm,
                                                  const double* Fp, const double* p,
                                                  double* Ap, double* sc, int it) {
    long i = (long)blockIdx.x * TPB + threadIdx.x;
    double* base = sc + 16 + 8 * it;
    double wt = Fp[NMSUM];
    double l = 0.0;
    if (i < N_DIM) {
        double v = Ap[i] - c3[i] * wt;
        Ap[i] = v;
        l = p[i] * v;
    } else if (i < NMSUM) {
        int j = (int)(i - N_DIM);
        double tmv = tm[j] - (double)b[j] * wt;
        double wm = Fp[i];
        double v = mask_d[j] * (tmv - wm) + wm;
        Ap[i] = v;
        l = p[i] * v;
    } else if (i == NMSUM) {
        double tt = base[2] + base[3] + sc[0] * wt;
        Ap[i] = tt;
        l = p[i] * tt;
    }
    blk_red_add(l, base + 4);   // pq
}

// K6: x,r update + gam[it+1]
__global__ __launch_bounds__(TPB) void k_upd(const double* p, const double* Ap,
                                             double* xcg, double* r, double* sc, int it) {
    long i = (long)blockIdx.x * TPB + threadIdx.x;
    double* gam = sc + 432;
    double* base = sc + 16 + 8 * it;
    double alpha = gam[it] / base[4];
    double l = 0.0;
    if (i < NM1) {
        xcg[i] += alpha * p[i];
        double rn = r[i] - alpha * Ap[i];
        r[i] = rn;
        l = rn * rn;
    }
    blk_red_add(l, &gam[it + 1]);
}

__global__ __launch_bounds__(TPB) void k_final(const double* xcg, const double* mask_d,
                                               const float* x, const float* y, const float* s,
                                               float* out) {
    int i = blockIdx.x * TPB + threadIdx.x;
    double dzt = xcg[NMSUM];
    if (i < N_DIM) {
        out[i] = (float)(xcg[i] - (double)x[i] * dzt);
    } else if (i < NMSUM) {
        int j = i - N_DIM;
        double dzm = xcg[N_DIM + j];
        double t = mask_d[j] * dzm;
        out[N_DIM + j] = (float)(t - (double)y[j] * dzt);
        out[N_DIM + M_DIM + j] = (float)(t - dzm - (double)s[j] * dzt);
    }
}

extern "C" void kernel_launch(void* const* d_in, const int* in_sizes, int n_in,
                              void* d_out, int out_size, void* d_ws, size_t ws_size,
                              hipStream_t stream) {
    const int*   Pr  = (const int*)d_in[0];
    const int*   Pc  = (const int*)d_in[1];
    const float* Pv  = (const float*)d_in[2];
    const int*   Ar  = (const int*)d_in[3];
    const int*   Ac  = (const int*)d_in[4];
    const float* Av  = (const float*)d_in[5];
    const float* q   = (const float*)d_in[6];
    const float* b   = (const float*)d_in[7];
    const float* x   = (const float*)d_in[8];
    const float* yv  = (const float*)d_in[9];
    const float* sv  = (const float*)d_in[10];
    const float* dPv = (const float*)d_in[11];
    const float* dAv = (const float*)d_in[12];
    const float* dq  = (const float*)d_in[13];
    const float* db  = (const float*)d_in[14];
    float* out = (float*)d_out;

    char* wp = (char*)d_ws;
    double* sc     = (double*)wp; wp += NSLOT * 8;
    double* mask_d = (double*)wp; wp += M_DIM * 8;
    double* pim_d  = (double*)wp; wp += M_DIM * 8;
    double* Px     = (double*)wp; wp += N_DIM * 8;
    double* dpx    = (double*)wp; wp += N_DIM * 8;
    double* c3     = (double*)wp; wp += N_DIM * 8;
    double* um     = (double*)wp; wp += M_DIM * 8;
    double* tm     = (double*)wp; wp += M_DIM * 8;
    double* dd     = (double*)wp; wp += NM1 * 8;
    double* r      = (double*)wp; wp += NM1 * 8;
    double* p      = (double*)wp; wp += NM1 * 8;
    double* xcg    = (double*)wp; wp += NM1 * 8;
    double* Fp     = (double*)wp; wp += NM1 * 8;
    double* Ap     = (double*)wp; wp += NM1 * 8;

    double* xtpx = sc + 0;
    double* gam  = sc + 432;

    auto g = [](long n) { return dim3((unsigned)((n + TPB - 1) / TPB)); };

    // ---- setup (identical to passing R11 sequence) ----
    hipLaunchKernelGGL(k_init, g(NM1), dim3(TPB), 0, stream, sc, yv, sv, mask_d, pim_d, Px, dpx, dd, r, xcg, tm);
    hipLaunchKernelGGL(k_spf, g(NNZ_P), dim3(TPB), 0, stream, Pv, Pr, Pc, x, Px, 1.0, (long)NNZ_P);
    hipLaunchKernelGGL(k_dot_fd, g(N_DIM), dim3(TPB), 0, stream, x, Px, (long)N_DIM, xtpx);
    hipLaunchKernelGGL(k_c3e, g(N_DIM), dim3(TPB), 0, stream, q, Px, c3);
    hipLaunchKernelGGL(k_spf, g(NNZ_P), dim3(TPB), 0, stream, dPv, Pr, Pc, x, dpx, 1.0, (long)NNZ_P);
    hipLaunchKernelGGL(k_dd_n, g(N_DIM), dim3(TPB), 0, stream, dpx, dq, dd);
    hipLaunchKernelGGL(k_sp, g(NNZ_A), dim3(TPB), 0, stream, dAv, Ac, Ar, pim_d, dd, 1.0, (long)NNZ_A);
    hipLaunchKernelGGL(k_spf, g(NNZ_A), dim3(TPB), 0, stream, dAv, Ar, Ac, x, dd + N_DIM, -1.0, (long)NNZ_A);
    hipLaunchKernelGGL(k_dd_m, g(M_DIM), dim3(TPB), 0, stream, db, dd);
    hipLaunchKernelGGL(k_dot_ff, g(N_DIM), dim3(TPB), 0, stream, dq, x, (long)N_DIM, sc + 1);
    hipLaunchKernelGGL(k_dot_fd, g(M_DIM), dim3(TPB), 0, stream, db, pim_d, (long)M_DIM, sc + 2);
    hipLaunchKernelGGL(k_dot_fd, g(N_DIM), dim3(TPB), 0, stream, x, dpx, (long)N_DIM, sc + 3);
    hipLaunchKernelGGL(k_dd_t, dim3(1), dim3(64), 0, stream, sc, dd);
    hipLaunchKernelGGL(k_neg, g(NM1), dim3(TPB), 0, stream, dd);
    hipLaunchKernelGGL(k_sp, g(NNZ_P), dim3(TPB), 0, stream, Pv, Pr, Pc, dd, r, 1.0, (long)NNZ_P);
    hipLaunchKernelGGL(k_sp, g(NNZ_A), dim3(TPB), 0, stream, Av, Ac, Ar, dd + N_DIM, r, -1.0, (long)NNZ_A);
    hipLaunchKernelGGL(k_ft_n, g(N_DIM), dim3(TPB), 0, stream, c3, dd, r);
    hipLaunchKernelGGL(k_sp, g(NNZ_A), dim3(TPB), 0, stream, Av, Ar, Ac, dd, tm, 1.0, (long)NNZ_A);
    hipLaunchKernelGGL(k_ft_m, g(M_DIM), dim3(TPB), 0, stream, mask_d, b, tm, dd, r);
    hipLaunchKernelGGL(k_dot_fd, g(N_DIM), dim3(TPB), 0, stream, q, dd, (long)N_DIM, sc + 8);
    hipLaunchKernelGGL(k_dot_fd, g(M_DIM), dim3(TPB), 0, stream, b, dd + N_DIM, (long)M_DIM, sc + 9);
    hipLaunchKernelGGL(k_ft_t, dim3(1), dim3(64), 0, stream, sc + 8, sc + 9, xtpx, dd, r);
    hipLaunchKernelGGL(k_cginit, g(NM1), dim3(TPB), 0, stream, r, p, gam);

    // ---- 20 CG iterations, 6 fused launches each ----
    for (int it = 0; it < CG_ITERS; ++it) {
        hipLaunchKernelGGL(k_iterA,     g(NM1),   dim3(TPB), 0, stream, r, p, mask_d, c3, b, um, Fp, Ap, tm, sc, it);
        hipLaunchKernelGGL(k_fmv_scat,  g(NNZ_A), dim3(TPB), 0, stream, Pr, Pc, Pv, Ar, Ac, Av, p, um, Fp);
        hipLaunchKernelGGL(k_fmv_fin,   g(NM1),   dim3(TPB), 0, stream, q, b, p, um, Fp, sc, it);
        hipLaunchKernelGGL(k_ftmv_scat, g(NNZ_A), dim3(TPB), 0, stream, Pr, Pc, Pv, Ar, Ac, Av, Fp, Ap, tm);
        hipLaunchKernelGGL(k_ftmv_fin,  g(NM1),   dim3(TPB), 0, stream, b, mask_d, c3, tm, Fp, p, Ap, sc, it);
        hipLaunchKernelGGL(k_upd,       g(NM1),   dim3(TPB), 0, stream, p, Ap, xcg, r, sc, it);
    }

    hipLaunchKernelGGL(k_final, g(NMSUM), dim3(TPB), 0, stream, xcg, mask_d, x, yv, sv, out);
}